// Round 12
// baseline (416.897 us; speedup 1.0000x reference)
//
#include <hip/hip_runtime.h>

// ---------------- constants ----------------
#define NTOK 8192
#define NORMC 0.35355339059327373f   // 64^-0.25
#define RATIO 0.0625f                // 256^-0.5
#define KEPS  1e-4f

// ws offsets in 4-byte elements (total 27987008)
#define O_KMAX 0                      // 12 x u32 (encoded max)
#define O_KSUM 64                     // 12*256 f32  (zeroed region ends 3136)
#define O_CTX  3136                   // reused as WoT fp16 [512][512] after k_qout
#define O_COS  199744                 // 8192*32
#define O_SIN  461888                 // 8192*32
#define O_Q    724032                 // fp16 [2][8][8192][64] -> ends 4918336
#define O_K    9112640                // fp16 K; later attG fp16 [16384][384]
#define O_XH   13306944               // fp16 x [16384][512] (dead after k_qkv)
#define O_CPART 13306944              // fp16 ctx partials [12][2][32][128][64] in dead XH
#define O_V    17501248               // fp16 V
#define O_QR   21695552               // fp16 RoPE'd Q heads6-7
#define O_KR   22744128               // fp16 RoPE'd K heads6-7
#define O_ATTL 25889856               // fp16 [2][2][8192][64]
#define O_WH   25889856               // fp16 W^T [3][512][512] (dead after k_qkv)
#define O_PH   26938432               // fp16 proj [256][64]
#define O_CTXT 26946624               // fp16 ctxT [12][64][256] -> 27044928
// end of use: 27044928 < 27987008

typedef _Float16 half8 __attribute__((ext_vector_type(8)));
typedef _Float16 half4h __attribute__((ext_vector_type(4)));
typedef float floatx4 __attribute__((ext_vector_type(4)));

__device__ __forceinline__ unsigned encf(float f) {
    unsigned u = __float_as_uint(f);
    return (u & 0x80000000u) ? ~u : (u | 0x80000000u);
}
__device__ __forceinline__ float decf(unsigned u) {
    return (u & 0x80000000u) ? __uint_as_float(u & 0x7fffffffu) : __uint_as_float(~u);
}
__device__ __forceinline__ float sumsq8(half8 h) {
    float s = 0.f;
#pragma unroll
    for (int i = 0; i < 8; i++) { float v = (float)h[i]; s = fmaf(v, v, s); }
    return s;
}

// ---------------- RoPE tables (double precision angles) ----------------
__global__ void k_rope(float* __restrict__ ws) {
    int idx = blockIdx.x * 256 + threadIdx.x;      // 8192*32
    int t = idx >> 5, i = idx & 31;
    double invf = pow(10000.0, -(double)(2 * i) / 64.0);
    double ang = (double)t * invf;
    ws[O_COS + idx] = (float)cos(ang);
    ws[O_SIN + idx] = (float)sin(ang);
}

// ---------------- x -> fp16 ----------------
__launch_bounds__(256)
__global__ void k_half_x(const float* __restrict__ x, float* __restrict__ ws) {
    const int idx = blockIdx.x * 256 + threadIdx.x;   // *8 elements
    const float* p = x + (size_t)idx * 8;
    float4 a = *(const float4*)p, b = *(const float4*)(p + 4);
    half8 h = {(_Float16)a.x, (_Float16)a.y, (_Float16)a.z, (_Float16)a.w,
               (_Float16)b.x, (_Float16)b.y, (_Float16)b.z, (_Float16)b.w};
    *(half8*)((_Float16*)(ws + O_XH) + (size_t)idx * 8) = h;
}

// ---------------- proj -> fp16 [256][64] ----------------
__launch_bounds__(256)
__global__ void k_half_p(const float* __restrict__ proj, float* __restrict__ ws) {
    const int idx = blockIdx.x * 256 + threadIdx.x;
    const float* p = proj + (size_t)idx * 8;
    float4 a = *(const float4*)p, b = *(const float4*)(p + 4);
    half8 h = {(_Float16)a.x, (_Float16)a.y, (_Float16)a.z, (_Float16)a.w,
               (_Float16)b.x, (_Float16)b.y, (_Float16)b.z, (_Float16)b.w};
    *(half8*)((_Float16*)(ws + O_PH) + (size_t)idx * 8) = h;
}

// ---------------- RoPE'd Q/K fp16 for local heads 6..7, precomputed once ----------------
__launch_bounds__(256)
__global__ void k_ropeqk(float* __restrict__ ws) {
    const int idx = blockIdx.x * 256 + threadIdx.x;   // 32768 rows * 4 thr/row
    const int rg = idx >> 2, dqo = (idx & 3) * 16;
    const int b = rg >> 14, lh = (rg >> 13) & 1, n = rg & 8191;
    const int h = 6 + lh;
    const int e = dqo & 31;
    const int comp = (dqo < 32) ? dqo + 32 : dqo - 32;
    const float sgn = (dqo < 32) ? -1.f : 1.f;
    const _Float16* Qs = (const _Float16*)(ws + O_Q) + ((size_t)(b * 8 + h) * 8192 + n) * 64;
    const _Float16* Ks = (const _Float16*)(ws + O_K) + ((size_t)(b * 8 + h) * 8192 + n) * 64;
    _Float16* Qd = (_Float16*)(ws + O_QR) + ((size_t)(b * 2 + lh) * 8192 + n) * 64;
    _Float16* Kd = (_Float16*)(ws + O_KR) + ((size_t)(b * 2 + lh) * 8192 + n) * 64;
    const float* cp = ws + O_COS + n * 32 + e;
    const float* sp = ws + O_SIN + n * 32 + e;
    _Float16 tq[16], tk[16];
#pragma unroll
    for (int w4 = 0; w4 < 4; w4++) {
        float4 c4 = *(const float4*)(cp + 4 * w4);
        float4 s4v = *(const float4*)(sp + 4 * w4);
        half4h qa = *(const half4h*)(Qs + dqo + 4 * w4);
        half4h qb = *(const half4h*)(Qs + comp + 4 * w4);
        half4h ka = *(const half4h*)(Ks + dqo + 4 * w4);
        half4h kb = *(const half4h*)(Ks + comp + 4 * w4);
        tq[4*w4+0] = (_Float16)fmaf(sgn * (float)qb[0], s4v.x, (float)qa[0] * c4.x);
        tq[4*w4+1] = (_Float16)fmaf(sgn * (float)qb[1], s4v.y, (float)qa[1] * c4.y);
        tq[4*w4+2] = (_Float16)fmaf(sgn * (float)qb[2], s4v.z, (float)qa[2] * c4.z);
        tq[4*w4+3] = (_Float16)fmaf(sgn * (float)qb[3], s4v.w, (float)qa[3] * c4.w);
        tk[4*w4+0] = (_Float16)fmaf(sgn * (float)kb[0], s4v.x, (float)ka[0] * c4.x);
        tk[4*w4+1] = (_Float16)fmaf(sgn * (float)kb[1], s4v.y, (float)ka[1] * c4.y);
        tk[4*w4+2] = (_Float16)fmaf(sgn * (float)kb[2], s4v.z, (float)ka[2] * c4.z);
        tk[4*w4+3] = (_Float16)fmaf(sgn * (float)kb[3], s4v.w, (float)ka[3] * c4.w);
    }
    *(half8*)(Qd + dqo)     = *(half8*)&tq[0];
    *(half8*)(Qd + dqo + 8) = *(half8*)&tq[8];
    *(half8*)(Kd + dqo)     = *(half8*)&tk[0];
    *(half8*)(Kd + dqo + 8) = *(half8*)&tk[8];
}

// ---------------- ctx partials fp16 [12][2][32][128][64] -> ctxT fp16 [12][64][256] ------
__launch_bounds__(256)
__global__ void k_ctxt(float* __restrict__ ws) {
    __shared__ float T[16][65];
    const int bh = blockIdx.x, j0 = blockIdx.y * 16;      // 16 j per block
    const int jh = j0 >> 7, jrel0 = j0 & 127;
    const _Float16* __restrict__ pp =
        (const _Float16*)(ws + O_CPART) + ((size_t)(bh * 2 + jh) * 32) * 8192;
    _Float16* __restrict__ ct = (_Float16*)(ws + O_CTXT) + (size_t)bh * 16384;
    const int tid = threadIdx.x;
    const int lx = tid & 63, ly = tid >> 6;               // lx=d, ly covers 4 j
#pragma unroll
    for (int i = 0; i < 4; i++) {
        const int jl = ly * 4 + i;
        float s = 0.f;
#pragma unroll 8
        for (int sl = 0; sl < 32; sl++)
            s += (float)pp[((size_t)sl * 128 + jrel0 + jl) * 64 + lx];
        T[jl][lx] = s;
    }
    __syncthreads();
    const int d = tid >> 2, j4 = (tid & 3) * 4;
    half4h v;
#pragma unroll
    for (int ii = 0; ii < 4; ii++) v[ii] = (_Float16)T[j4 + ii][d];
    *(half4h*)(ct + d * 256 + j0 + j4) = v;
}

// ---------------- W -> fp16, transposed to [n][k] ----------------
__launch_bounds__(256)
__global__ void k_half_w(const float* __restrict__ Wq,
                         const float* __restrict__ Wk,
                         const float* __restrict__ Wv,
                         float* __restrict__ ws) {
    __shared__ float T[64][65];
    const int z = blockIdx.z;
    const float* __restrict__ W = (z == 0) ? Wq : ((z == 1) ? Wk : Wv);
    _Float16* __restrict__ Wt = (_Float16*)(ws + O_WH) + (size_t)z * 262144;
    const int k0 = blockIdx.x * 64, n0 = blockIdx.y * 64;
    const int lx = threadIdx.x & 63, ly = threadIdx.x >> 6;
#pragma unroll
    for (int i = 0; i < 16; i++) {
        const int kk = ly * 16 + i;
        T[lx][kk] = W[(k0 + kk) * 512 + n0 + lx];
    }
    __syncthreads();
#pragma unroll
    for (int i = 0; i < 16; i++) {
        const int nn = ly * 16 + i;
        Wt[(n0 + nn) * 512 + k0 + lx] = (_Float16)T[nn][lx];
    }
}

// ---------------- Wo -> fp16 transposed [n][k], into dead ctx region ----------------
__launch_bounds__(256)
__global__ void k_half_wo(const float* __restrict__ Wo, float* __restrict__ ws) {
    __shared__ float T[64][65];
    _Float16* __restrict__ Wt = (_Float16*)(ws + O_CTX);
    const int k0 = blockIdx.x * 64, n0 = blockIdx.y * 64;
    const int lx = threadIdx.x & 63, ly = threadIdx.x >> 6;
#pragma unroll
    for (int i = 0; i < 16; i++) {
        const int kk = ly * 16 + i;
        T[lx][kk] = Wo[(k0 + kk) * 512 + n0 + lx];
    }
    __syncthreads();
#pragma unroll
    for (int i = 0; i < 16; i++) {
        const int nn = ly * 16 + i;
        Wt[(n0 + nn) * 512 + k0 + lx] = (_Float16)T[nn][lx];
    }
}

// ---------------- QKV projection via fp16 MFMA (stride-68 LDS, coalesced epilogue) ------
// Stride 68 halfs (136 B): rows 8 apart land 16 banks apart -> staging ds_write_b128
// conflicts drop from 4-way (stride 72) to free; fragment reads conflict-free.
__launch_bounds__(256)
__global__ void k_qkv(float* __restrict__ ws) {
    __shared__ _Float16 SM[2 * 128 * 68];    // Ah | Bh; reused as out tile [128][136]
    _Float16* Ah = SM;
    _Float16* Bh = SM + 128 * 68;
    const int z = blockIdx.z;
    const _Float16* __restrict__ xh = (const _Float16*)(ws + O_XH);
    const _Float16* __restrict__ Wt = (const _Float16*)(ws + O_WH) + (size_t)z * 262144;
    _Float16* __restrict__ out = (_Float16*)(ws + ((z == 0) ? O_Q : ((z == 1) ? O_K : O_V)));
    const int r0 = blockIdx.x * 128, c0 = blockIdx.y * 128;
    const int tid = threadIdx.x;
    const int wv = tid >> 6, lane = tid & 63, lm = lane & 15, lq = lane >> 4;
    const int srow = tid >> 1, skoff = (tid & 1) * 32;
    floatx4 acc[2][8];
#pragma unroll
    for (int m = 0; m < 2; m++)
#pragma unroll
        for (int n = 0; n < 8; n++) acc[m][n] = (floatx4){0.f, 0.f, 0.f, 0.f};

    for (int c = 0; c < 8; c++) {
        const int k0 = c * 64;
        {
            const _Float16* ap = xh + (size_t)(r0 + srow) * 512 + k0 + skoff;
#pragma unroll
            for (int q = 0; q < 4; q++)
                *(uint4*)&Ah[srow * 68 + skoff + 8 * q] = *(const uint4*)(ap + 8 * q);
        }
        {
            const _Float16* bp = Wt + (size_t)(c0 + srow) * 512 + k0 + skoff;
#pragma unroll
            for (int q = 0; q < 4; q++)
                *(uint4*)&Bh[srow * 68 + skoff + 8 * q] = *(const uint4*)(bp + 8 * q);
        }
        __syncthreads();
#pragma unroll
        for (int ks = 0; ks < 2; ks++) {
            half8 af[2], bf[8];
            af[0] = *(half8*)&Ah[(wv * 32 + lm) * 68 + ks * 32 + lq * 8];
            af[1] = *(half8*)&Ah[(wv * 32 + 16 + lm) * 68 + ks * 32 + lq * 8];
#pragma unroll
            for (int n = 0; n < 8; n++)
                bf[n] = *(half8*)&Bh[(n * 16 + lm) * 68 + ks * 32 + lq * 8];
#pragma unroll
            for (int m = 0; m < 2; m++)
#pragma unroll
                for (int n = 0; n < 8; n++)
                    acc[m][n] = __builtin_amdgcn_mfma_f32_16x16x32_f16(af[m], bf[n], acc[m][n], 0, 0, 0);
        }
        __syncthreads();
    }
    // epilogue: restage C tile into SM [128][136] fp16 then coalesced 16B stores
    // (safe: last loop iteration ended with __syncthreads())
#pragma unroll
    for (int n = 0; n < 8; n++)
#pragma unroll
        for (int m = 0; m < 2; m++)
#pragma unroll
            for (int j = 0; j < 4; j++)
                SM[(wv * 32 + m * 16 + lq * 4 + j) * 136 + n * 16 + lm] =
                    (_Float16)acc[m][n][j];
    __syncthreads();
    const int bi = r0 >> 13;
    const int orow = tid >> 1, oh2 = tid & 1;
    const int ng = (r0 + orow) & 8191;
    const int hh = (c0 >> 6) + oh2;
    _Float16* op = out + ((size_t)(bi * 8 + hh) * 8192 + ng) * 64;
#pragma unroll
    for (int q = 0; q < 8; q++)
        *(uint4*)(op + q * 8) = *(uint4*)&SM[orow * 136 + oh2 * 64 + q * 8];
}

// ---------------- key-side global max of dd = norm*(K.projT) (fp16 MFMA) ----------------
__launch_bounds__(256)
__global__ void k_kmax(float* __restrict__ ws) {
    __shared__ _Float16 Kh[64 * 68];
    __shared__ unsigned bmax;
    const int bh = blockIdx.y, b = bh / 6, h = bh % 6;
    const _Float16* __restrict__ Kp = (const _Float16*)(ws + O_K) + (size_t)(b * 8 + h) * 8192 * 64;
    const _Float16* __restrict__ projh = (const _Float16*)(ws + O_PH);
    const int n0 = blockIdx.x * 64;
    const int tid = threadIdx.x;
    const int wv = tid >> 6, lane = tid & 63, lm = lane & 15, lq = lane >> 4;
    if (tid == 0) bmax = 0u;
    {
        const int r = tid >> 2, dq = (tid & 3) * 16;
        const _Float16* kpp = Kp + (size_t)(n0 + r) * 64 + dq;
        *(uint4*)&Kh[r * 68 + dq]     = *(const uint4*)(kpp);
        *(uint4*)&Kh[r * 68 + dq + 8] = *(const uint4*)(kpp + 8);
    }
    __syncthreads();
    floatx4 s4[4][4];
#pragma unroll
    for (int nt = 0; nt < 4; nt++)
#pragma unroll
        for (int jt = 0; jt < 4; jt++) s4[nt][jt] = (floatx4){0.f, 0.f, 0.f, 0.f};
#pragma unroll
    for (int ks = 0; ks < 2; ks++) {
        half8 af[4], bf[4];
#pragma unroll
        for (int nt = 0; nt < 4; nt++)
            af[nt] = *(half8*)&Kh[(nt * 16 + lm) * 68 + ks * 32 + lq * 8];
#pragma unroll
        for (int jt = 0; jt < 4; jt++)
            bf[jt] = *(const half8*)(projh + (wv * 64 + jt * 16 + lm) * 64 + ks * 32 + lq * 8);
#pragma unroll
        for (int nt = 0; nt < 4; nt++)
#pragma unroll
            for (int jt = 0; jt < 4; jt++)
                s4[nt][jt] = __builtin_amdgcn_mfma_f32_16x16x32_f16(af[nt], bf[jt], s4[nt][jt], 0, 0, 0);
    }
    float m = -1e30f;
#pragma unroll
    for (int nt = 0; nt < 4; nt++)
#pragma unroll
        for (int jt = 0; jt < 4; jt++)
#pragma unroll
            for (int r = 0; r < 4; r++) m = fmaxf(m, s4[nt][jt][r]);
    m = fmaxf(m, __shfl_xor(m, 1, 64));
    m = fmaxf(m, __shfl_xor(m, 2, 64));
    m = fmaxf(m, __shfl_xor(m, 4, 64));
    m = fmaxf(m, __shfl_xor(m, 8, 64));
    m = fmaxf(m, __shfl_xor(m, 16, 64));
    m = fmaxf(m, __shfl_xor(m, 32, 64));
    if (lane == 0) atomicMax(&bmax, encf(m * NORMC));
    __syncthreads();
    if (tid == 0) atomicMax((unsigned*)ws + O_KMAX + bh, bmax);
}

// ---------------- key-side: kp, k_sum, ctx partials (fp16 MFMA, coalesced flush) --------
__launch_bounds__(256)
__global__ void k_kctx(float* __restrict__ ws) {
    __shared__ _Float16 Kh[64 * 68];
    __shared__ _Float16 Vt[64 * 68];
    __shared__ _Float16 kpt[128 * 72];   // qp use stride 68; flush restage stride 72
    __shared__ float diag4[64][4];
    __shared__ float ksum_s[128];
    const int bh = blockIdx.y, b = bh / 6, h = bh % 6;
    const int n0 = blockIdx.x * 256;
    const int jh = blockIdx.z;
    const _Float16* __restrict__ Kp = (const _Float16*)(ws + O_K) + (size_t)(b * 8 + h) * 8192 * 64;
    const _Float16* __restrict__ Vp = (const _Float16*)(ws + O_V) + (size_t)(b * 8 + h) * 8192 * 64;
    const _Float16* __restrict__ projh = (const _Float16*)(ws + O_PH);
    const float kmax = decf(((const unsigned*)ws)[O_KMAX + bh]);
    const int tid = threadIdx.x;
    const int wv = tid >> 6, lane = tid & 63, lm = lane & 15, lq = lane >> 4;
    if (tid < 128) ksum_s[tid] = 0.f;

    floatx4 acc[2][4];
#pragma unroll
    for (int jt = 0; jt < 2; jt++)
#pragma unroll
        for (int dt = 0; dt < 4; dt++) acc[jt][dt] = (floatx4){0.f, 0.f, 0.f, 0.f};

    for (int nc = 0; nc < 4; nc++) {
        const int ns = n0 + nc * 64;
        if (nc) __syncthreads();                  // D: prev chunk's LDS reads done
        {   // stage Kh [n][d] fp16 copy + diag partials
            const int r = tid >> 2, dq = (tid & 3) * 16;
            const _Float16* kpp = Kp + (size_t)(ns + r) * 64 + dq;
            half8 h0 = *(const half8*)(kpp);
            half8 h1 = *(const half8*)(kpp + 8);
            *(half8*)&Kh[r * 68 + dq]     = h0;
            *(half8*)&Kh[r * 68 + dq + 8] = h1;
            diag4[r][tid & 3] = sumsq8(h0) + sumsq8(h1);
        }
        {   // stage Vt transposed [d][n]
            const int d = tid & 63, nb = (tid >> 6) * 16;
            _Float16 t[16];
#pragma unroll
            for (int i = 0; i < 16; i++)
                t[i] = Vp[(size_t)(ns + nb + i) * 64 + d];
            *(half8*)&Vt[d * 68 + nb]     = *(half8*)&t[0];
            *(half8*)&Vt[d * 68 + nb + 8] = *(half8*)&t[8];
        }
        __syncthreads();                          // A: staging visible
        floatx4 s4[4][2];
#pragma unroll
        for (int nt = 0; nt < 4; nt++)
#pragma unroll
            for (int jt = 0; jt < 2; jt++) s4[nt][jt] = (floatx4){0.f, 0.f, 0.f, 0.f};
#pragma unroll
        for (int ks = 0; ks < 2; ks++) {
            half8 af[4], bf[2];
#pragma unroll
            for (int nt = 0; nt < 4; nt++)
                af[nt] = *(half8*)&Kh[(nt * 16 + lm) * 68 + ks * 32 + lq * 8];
#pragma unroll
            for (int jt = 0; jt < 2; jt++)
                bf[jt] = *(const half8*)(projh + (jh * 128 + wv * 32 + jt * 16 + lm) * 64 + ks * 32 + lq * 8);
#pragma unroll
            for (int nt = 0; nt < 4; nt++)
#pragma unroll
                for (int jt = 0; jt < 2; jt++)
                    s4[nt][jt] = __builtin_amdgcn_mfma_f32_16x16x32_f16(af[nt], bf[jt], s4[nt][jt], 0, 0, 0);
        }
        float jsum[2] = {0.f, 0.f};
#pragma unroll
        for (int nt = 0; nt < 4; nt++) {
            float dg[4];
#pragma unroll
            for (int rr = 0; rr < 4; rr++) {
                float4 d4 = *(float4*)diag4[nt * 16 + lq * 4 + rr];
                dg[rr] = (d4.x + d4.y + d4.z + d4.w) * 0.0625f;
            }
#pragma unroll
            for (int jt = 0; jt < 2; jt++) {
                half4h kv;
#pragma unroll
                for (int rr = 0; rr < 4; rr++) {
                    float v = RATIO * (__expf(fminf(NORMC * s4[nt][jt][rr] - dg[rr] - kmax, 0.f)) + KEPS);
                    jsum[jt] += v;
                    kv[rr] = (_Float16)v;
                }
                *(half4h*)&kpt[(wv * 32 + jt * 16 + lm) * 68 + nt * 16 + lq * 4] = kv;
            }
        }
#pragma unroll
        for (int jt = 0; jt < 2; jt++)
            atomicAdd(&ksum_s[wv * 32 + jt * 16 + lm], jsum[jt]);
        asm volatile("s_waitcnt lgkmcnt(0)" ::: "memory");
#pragma unroll
        for (int ks = 0; ks < 2; ks++) {
            half8 af[2], bf[4];
#pragma unroll
            for (int jt = 0; jt < 2; jt++)
                af[jt] = *(half8*)&kpt[(wv * 32 + jt * 16 + lm) * 68 + ks * 32 + lq * 8];
#pragma unroll
            for (int dt = 0; dt < 4; dt++)
                bf[dt] = *(half8*)&Vt[(dt * 16 + lm) * 68 + ks * 32 + lq * 8];
#pragma unroll
            for (int jt = 0; jt < 2; jt++)
#pragma unroll
                for (int dt = 0; dt < 4; dt++)
                    acc[jt][dt] = __builtin_amdgcn_mfma_f32_16x16x32_f16(af[jt], bf[dt], acc[jt][dt], 0, 0, 0);
        }
    }
    // RACE FIX: all waves must finish reading kpt (stride 68) before the stride-72
    // restage overwrites overlapping bytes of neighboring waves' rows.
    __syncthreads();
    // restage acc into kpt [128][72] (wave-private rows), then coalesced 16B stores
#pragma unroll
    for (int jt = 0; jt < 2; jt++)
#pragma unroll
        for (int dt = 0; dt < 4; dt++)
#pragma unroll
            for (int rr = 0; rr < 4; rr++)
                kpt[(wv * 32 + jt * 16 + lq * 4 + rr) * 72 + dt * 16 + lm] =
                    (_Float16)acc[jt][dt][rr];
    __syncthreads();   // restage + ksum complete
    _Float16* __restrict__ cp = (_Float16*)(ws + O_CPART) +
        (((size_t)(bh * 2 + jh) * 32 + blockIdx.x) * 128) * 64;
    const int jl = tid >> 1, hf = (tid & 1) * 32;
#pragma unroll
    for (int q = 0; q < 4; q++)
        *(uint4*)(cp + jl * 64 + hf + q * 8) = *(uint4*)&kpt[jl * 72 + hf + q * 8];
    if (tid < 128) atomicAdd(ws + O_KSUM + bh * 256 + jh * 128 + tid, ksum_s[tid]);
}

// ---------------- query-side: dd, rowmax, qp, attG (j-sliced, coalesced epilogue) -------
__launch_bounds__(256)
__global__ void k_qout(float* __restrict__ ws) {
    __shared__ _Float16 Qh[64 * 68];
    __shared__ _Float16 qp_s[64 * 260];   // qp stride 260; reused as out tile stride 72
    __shared__ float ksum_s[256];
    __shared__ float diag4[64][4];
    __shared__ float diag_s[64];
    __shared__ unsigned rmax_s[64];
    __shared__ float denom_s[64];
    const int bh = blockIdx.y, b = bh / 6, h = bh % 6;
    const int n0 = blockIdx.x * 64;
    const _Float16* __restrict__ Qp = (const _Float16*)(ws + O_Q) + (size_t)(b * 8 + h) * 8192 * 64;
    const _Float16* __restrict__ projh = (const _Float16*)(ws + O_PH);
    const _Float16* __restrict__ ct = (const _Float16*)(ws + O_CTXT) + (size_t)bh * 16384;
    _Float16* __restrict__ attG = (_Float16*)(ws + O_K);
    const int tid = threadIdx.x;
    const int wv = tid >> 6, lane = tid & 63, lm = lane & 15, lq = lane >> 4;
    if (tid < 64) { rmax_s[tid] = 0u; denom_s[tid] = 0.f; }
    ksum_s[tid] = ws[O_KSUM + bh * 256 + tid];

    {
        const int r = tid >> 2, dq = (tid & 3) * 16;
        const _Float16* qpp = Qp + (size_t)(n0 + r) * 64 + dq;
        half8 h0 = *(const half8*)(qpp);
        half8 h1 = *(const half8*)(qpp + 8);
        *(half8*)&Qh[r * 68 + dq]     = h0;
        *(half8*)&Qh[r * 68 + dq + 8] = h1;
        diag4[r][tid & 3] = sumsq8(h0) + sumsq8(h1);
    }
    __syncthreads();
    if (tid < 64) {
        float4 d4 = *(float4*)diag4[tid];
        diag_s[tid] = (d4.x + d4.y + d4.z + d4.w) * 0.0625f;
    }
    floatx4 s4[4][4];
#pragma unroll
    for (int nt = 0; nt < 4; nt++)
#pragma unroll
        for (int jt = 0; jt < 4; jt++) s4[nt][jt] = (floatx4){0.f, 0.f, 0.f, 0.f};
#pragma unroll
    for (int ks = 0; ks < 2; ks++) {
        half8 af[4], bf[4];
#pragma unroll
        for (int nt = 0; nt < 4; nt++)
            af[nt] = *(half8*)&Qh[(nt * 16 + lm) * 68 + ks * 32 + lq * 8];
#pragma unroll
        for (int jt = 0; jt < 4; jt++)
            bf[jt] = *(const half8*)(projh + (wv * 64 + jt * 16 + lm) * 64 + ks * 32 + lq * 8);
#pragma unroll
        for (int nt = 0; nt < 4; nt++)
#pragma unroll
            for (int jt = 0; jt < 4; jt++)
                s4[nt][jt] = __builtin_amdgcn_mfma_f32_16x16x32_f16(af[nt], bf[jt], s4[nt][jt], 0, 0, 0);
    }
#pragma unroll
    for (int nt = 0; nt < 4; nt++) {
#pragma unroll
        for (int rr = 0; rr < 4; rr++) {
            float m0 = fmaxf(fmaxf(s4[nt][0][rr], s4[nt][1][rr]),
                             fmaxf(s4[nt][2][rr], s4[nt][3][rr]));
            m0 = fmaxf(m0, __shfl_xor(m0, 1, 64));
            m0 = fmaxf(m0, __shfl_xor(m0, 2, 64));
            m0 = fmaxf(m0, __shfl_xor(m0, 4, 64));
            m0 = fmaxf(m0, __shfl_xor(m0, 8, 64));
            if (lm == 0) atomicMax(&rmax_s[nt * 16 + lq * 4 + rr], encf(m0 * NORMC));
        }
    }
    __syncthreads();
#pragma unroll
    for (int nt = 0; nt < 4; nt++) {
#pragma unroll
        for (int rr = 0; rr < 4; rr++) {
            const int row = nt * 16 + lq * 4 + rr;
            const float rmx = decf(rmax_s[row]);
            const float dgv = diag_s[row];
#pragma unroll
            for (int jt = 0; jt < 4; jt++) {
                const int j = wv * 64 + jt * 16 + lm;
                float v = RATIO * (__expf(fminf(NORMC * s4[nt][jt][rr] - dgv - rmx, 0.f)) + KEPS);
                qp_s[row * 260 + j] = (_Float16)v;
                s4[nt][jt][rr] = v * ksum_s[j];
            }
            float ds = s4[nt][0][rr] + s4[nt][1][rr] + s4[nt][2][rr] + s4[nt][3][rr];
            ds += __shfl_xor(ds, 1, 64);
            ds += __shfl_xor(ds, 2, 64);
            ds += __shfl_xor(ds, 4, 64);
            ds += __shfl_xor(ds, 8, 64);
            if (lm == 0) atomicAdd(&denom_s[row], ds);
        }
    }
    __syncthreads();
    floatx4 acc2[4];
#pragma unroll
    for (int nt = 0; nt < 4; nt++) acc2[nt] = (floatx4){0.f, 0.f, 0.f, 0.f};
#pragma unroll
    for (int ks = 0; ks < 8; ks++) {
        half8 bfv = *(const half8*)(ct + (wv * 16 + lm) * 256 + ks * 32 + lq * 8);
#pragma unroll
        for (int nt = 0; nt < 4; nt++) {
            half8 af = *(half8*)&qp_s[(nt * 16 + lm) * 260 + ks * 32 + lq * 8];
            acc2[nt] = __builtin_amdgcn_mfma_f32_16x16x32_f16(af, bfv, acc2[nt], 0, 0, 0);
        }
    }
    __syncthreads();   // all qp_s reads done -> reuse as out tile [64][72]
#pragma unroll
    for (int nt = 0; nt < 4; nt++) {
#pragma unroll
        for (int rr = 0; rr < 4; rr++) {
            const int row = nt * 16 + lq * 4 + rr;
            const float inv = 1.0f / fmaxf(denom_s[row], 1e-30f);
            qp_s[row * 72 + wv * 16 + lm] = (_Float16)(acc2[nt][rr] * inv);
        }
    }
    __syncthreads();
    const int orow = tid >> 2, od = (tid & 3) * 16;
    _Float16* op = attG + ((size_t)(b * 8192 + n0 + orow)) * 384 + h * 64 + od;
    *(uint4*)(op)     = *(uint4*)&qp_s[orow * 72 + od];
    *(uint4*)(op + 8) = *(uint4*)&qp_s[orow * 72 + od + 8];
}

// ---------------- local windowed attention, heads 6..7 (coalesced epilogue) -------------
__launch_bounds__(256)
__global__ void k_local(float* __restrict__ ws) {
    __shared__ _Float16 Kh[64 * 68];
    __shared__ _Float16 Vt[64 * 68];
    __shared__ _Float16 pT[64 * 72];     // P stride 68; epilogue restage stride 72
    const int bhp = blockIdx.x, b = bhp >> 1, lh = bhp & 1, h = 6 + lh;
    const int tile = blockIdx.y;
    const int w = tile >> 2;
    const int q0 = tile * 64;
    const _Float16* __restrict__ Qr = (const _Float16*)(ws + O_QR) + (size_t)(b * 2 + lh) * 8192 * 64;
    const _Float16* __restrict__ Kr = (const _Float16*)(ws + O_KR) + (size_t)(b * 2 + lh) * 8192 * 64;
    const _Float16* __restrict__ Vb = (const _Float16*)(ws + O_V) + (size_t)(b * 8 + h) * 8192 * 64;
    const int tid = threadIdx.x;
    const int wv = tid >> 6, lane = tid & 63, lm = lane & 15, lq = lane >> 4;
    const int row = tid >> 2, dqo = (tid & 3) * 16;
    const int vd = lane, vnb = wv * 16;

    const _Float16* qrow = Qr + (size_t)(q0 + wv * 16 + lm) * 64 + lq * 8;
    const half8 aq0 = *(const half8*)(qrow);
    const half8 aq1 = *(const half8*)(qrow + 32);

    const int clo = (w == 0) ? 4 : 0;
    const int chi = min(12, 132 - 4 * w);
    half8 kb0, kb1;
    _Float16 vb[16];
    {
        const int kp0 = (w - 1) * 256 + clo * 64;
        const _Float16* kp = Kr + (size_t)(kp0 + row) * 64 + dqo;
        kb0 = *(const half8*)(kp);
        kb1 = *(const half8*)(kp + 8);
#pragma unroll
        for (int i = 0; i < 16; i++) vb[i] = Vb[(size_t)(kp0 + vnb + i) * 64 + vd];
    }
    floatx4 O[4];
#pragma unroll
    for (int df = 0; df < 4; df++) O[df] = (floatx4){0.f, 0.f, 0.f, 0.f};
    float m_run[4] = {-1e30f, -1e30f, -1e30f, -1e30f};
    float l_run[4] = {0.f, 0.f, 0.f, 0.f};

    for (int c = clo; c < chi; c++) {
        if (c > clo) __syncthreads();
        *(half8*)&Kh[row * 68 + dqo]     = kb0;
        *(half8*)&Kh[row * 68 + dqo + 8] = kb1;
        *(half8*)&Vt[vd * 68 + vnb]     = *(half8*)&vb[0];
        *(half8*)&Vt[vd * 68 + vnb + 8] = *(half8*)&vb[8];
        __syncthreads();
        if (c + 1 < chi) {
            const int kp0 = (w - 1) * 256 + (c + 1) * 64;
            const _Float16* kp = Kr + (size_t)(kp0 + row) * 64 + dqo;
            kb0 = *(const half8*)(kp);
            kb1 = *(const half8*)(kp + 8);
#pragma unroll
            for (int i = 0; i < 16; i++) vb[i] = Vb[(size_t)(kp0 + vnb + i) * 64 + vd];
        }
        floatx4 s4[4];
#pragma unroll
        for (int nf = 0; nf < 4; nf++) s4[nf] = (floatx4){0.f, 0.f, 0.f, 0.f};
#pragma unroll
        for (int ks = 0; ks < 2; ks++) {
            half8 aq = ks ? aq1 : aq0;
            half8 bf[4];
#pragma unroll
            for (int nf = 0; nf < 4; nf++)
                bf[nf] = *(half8*)&Kh[(nf * 16 + lm) * 68 + ks * 32 + lq * 8];
#pragma unroll
            for (int nf = 0; nf < 4; nf++)
                s4[nf] = __builtin_amdgcn_mfma_f32_16x16x32_f16(aq, bf[nf], s4[nf], 0, 0, 0);
        }
        float p[4][4];
#pragma unroll
        for (int rr = 0; rr < 4; rr++) {
            float m0 = fmaxf(fmaxf(s4[0][rr], s4[1][rr]), fmaxf(s4[2][rr], s4[3][rr]));
            m0 = fmaxf(m0, __shfl_xor(m0, 1, 64));
            m0 = fmaxf(m0, __shfl_xor(m0, 2, 64));
            m0 = fmaxf(m0, __shfl_xor(m0, 4, 64));
            m0 = fmaxf(m0, __shfl_xor(m0, 8, 64));
            const float mn = fmaxf(m_run[rr], m0 * 0.125f);
            const float al = __expf(m_run[rr] - mn);
            m_run[rr] = mn;
            float rs = 0.f;
#pragma unroll
            for (int nf = 0; nf < 4; nf++) {
                float pv = __expf(fmaf(s4[nf][rr], 0.125f, -mn));
                p[nf][rr] = pv;
                rs += pv;
            }
            l_run[rr] = l_run[rr] * al + rs;
#pragma unroll
            for (int df = 0; df < 4; df++) O[df][rr] *= al;
        }
#pragma unroll
        for (int nf = 0; nf < 4; nf++)
#pragma unroll
            for (int rr = 0; rr < 4; rr++)
                pT[(wv * 16 + lq * 4 + rr) * 68 + nf * 16 + lm] = (_Float16)p[nf][rr];
        asm volatile("s_waitcnt lgkmcnt(0)" ::: "memory");
#pragma unroll
        for (int ks = 0; ks < 2; ks++) {
            half8 ap = *(half8*)&pT[(wv * 16 + lm) * 68 + ks * 32 + lq * 8];
            half8 bf[4];
#pragma unroll
            for (int df = 0; df < 4; df++)
                bf[df] = *(half8*)&Vt[(df * 16 + lm) * 68 + ks * 32 + lq * 8];
#pragma unroll
            for (int df = 0; df < 4; df++)
                O[df] = __builtin_amdgcn_mfma_f32_16x16x32_f16(ap, bf[df], O[df], 0, 0, 0);
        }
    }
#pragma unroll
    for (int rr = 0; rr < 4; rr++) {
        l_run[rr] += __shfl_xor(l_run[rr], 1, 64);
        l_run[rr] += __shfl_xor(l_run[rr], 2, 64);
        l_run[rr] += __shfl_xor(l_run[rr], 4, 64);
        l_run[rr] += __shfl_xor(l_run[rr], 8, 64);
        l_run[rr] = 1.f / fmaxf(l_run[rr], 1e-30f);
    }
    // RACE FIX: all waves must finish reading pT (stride 68) before the stride-72
    // restage overwrites overlapping bytes of neighboring waves' rows.
    __syncthreads();
    // restage O into pT [64][72] (wave-private rows), then coalesced stores
#pragma unroll
    for (int df = 0; df < 4; df++)
#pragma unroll
        for (int rr = 0; rr < 4; rr++)
            pT[(wv * 16 + lq * 4 + rr) * 72 + df * 16 + lm] =
                (_Float16)(O[df][rr] * l_run[rr]);
    __syncthreads();
    _Float16* __restrict__ attL = (_Float16*)(ws + O_ATTL);
    const int qrw = tid >> 2, dseg = (tid & 3) * 16;
    _Float16* op = attL + ((size_t)(b * 2 + lh) * 8192 + q0 + qrw) * 64 + dseg;
    *(uint4*)(op)     = *(uint4*)&pT[qrw * 72 + dseg];
    *(uint4*)(op + 8) = *(uint4*)&pT[qrw * 72 + dseg + 8];
}

// ---------------- output projection + bias (fp16 MFMA) ----------------
__launch_bounds__(256)
__global__ void k_out(const float* __restrict__ bo,
                      const float* __restrict__ ws,
                      float* __restrict__ out) {
    __shared__ _Float16 Ah[128 * 72];
    __shared__ _Float16 Bh[128 * 72];
    const _Float16* __restrict__ attG = (const _Float16*)(ws + O_K);
    const _Float16* __restrict__ attL = (const _Float16*)(ws + O_ATTL);
    const _Float16* __restrict__ WoT = (const _Float16*)(ws + O_CTX);
    const int r0 = blockIdx.x * 128, c0 = blockIdx.y * 128;
    const int tid = threadIdx.x;
    const int wv = tid >> 6, lane = tid & 63, lm = lane & 15, lq = lane >> 4;
    const int srow = tid >> 1, skoff = (tid & 1) * 32;
    floatx4 acc[2][8];
#pragma unroll
    for (int m = 0; m < 2; m++)
#pragma unroll
        for (int n = 0; n < 8; n++) acc[m][n] = (floatx4){0.f, 0.f, 0.f, 0.f};

    for (int c = 0; c < 8; c++) {
        const int k0 = c * 64;
        {
            const int row = r0 + srow;
            const int kk = k0 + skoff;
            const _Float16* ap;
            if (kk < 384) {
                ap = attG + (size_t)row * 384 + kk;
            } else {
                const int bb = row >> 13, nn = row & 8191;
                const int kr = kk - 384;
                ap = attL + ((size_t)(bb * 2 + (kr >> 6)) * 8192 + nn) * 64 + (kr & 63);
            }
#pragma unroll
            for (int q = 0; q < 4; q++)
                *(uint4*)&Ah[srow * 72 + skoff + 8 * q] = *(const uint4*)(ap + 8 * q);
        }
        {
            const _Float16* bp = WoT + (size_t)(c0 + srow) * 512 + k0 + skoff;
#pragma unroll
            for (int q = 0; q < 4; q++)
                *(uint4*)&Bh[srow * 72 + skoff + 8 * q] = *(const uint4*)(bp + 8 * q);
        }
        __syncthreads();
#pragma unroll
        for (int ks = 0; ks < 2; ks++) {
            half8 af[2], bf[8];
            af[0] = *(half8*)&Ah[(wv * 32 + lm) * 72 + ks * 32 + lq * 8];
            af[1] = *(half8*)&Ah[(wv * 32 + 16 + lm) * 72 + ks * 32 + lq * 8];
#pragma unroll
            for (int n = 0; n < 8; n++)
                bf[n] = *(half8*)&Bh[(n * 16 + lm) * 72 + ks * 32 + lq * 8];
#pragma unroll
            for (int m = 0; m < 2; m++)
#pragma unroll
                for (int n = 0; n < 8; n++)
                    acc[m][n] = __builtin_amdgcn_mfma_f32_16x16x32_f16(af[m], bf[n], acc[m][n], 0, 0, 0);
        }
        __syncthreads();
    }
#pragma unroll
    for (int n = 0; n < 8; n++) {
        const int col = c0 + n * 16 + lm;
        const float bias = bo[col];
#pragma unroll
        for (int m = 0; m < 2; m++) {
            const int rbase = r0 + wv * 32 + m * 16 + lq * 4;
#pragma unroll
            for (int j = 0; j < 4; j++)
                out[(size_t)(rbase + j) * 512 + col] = acc[m][n][j] + bias;
        }
    }
}

extern "C" void kernel_launch(void* const* d_in, const int* in_sizes, int n_in,
                              void* d_out, int out_size, void* d_ws, size_t ws_size,
                              hipStream_t stream) {
    const float* x    = (const float*)d_in[0];
    const float* Wq   = (const float*)d_in[1];
    const float* Wk   = (const float*)d_in[2];
    const float* Wv   = (const float*)d_in[3];
    const float* Wo   = (const float*)d_in[4];
    const float* bo   = (const float*)d_in[5];
    const float* proj = (const float*)d_in[6];
    float* ws = (float*)d_ws;
    float* out = (float*)d_out;

    hipMemsetAsync(d_ws, 0, (size_t)3136 * 4, stream);                   // kmax/ksum only
    hipLaunchKernelGGL(k_rope,   dim3(1024), dim3(256), 0, stream, ws);
    hipLaunchKernelGGL(k_half_x, dim3(4096), dim3(256), 0, stream, x, ws);
    hipLaunchKernelGGL(k_half_w, dim3(8, 8, 3), dim3(256), 0, stream, Wq, Wk, Wv, ws);
    hipLaunchKernelGGL(k_qkv,    dim3(128, 4, 3), dim3(256), 0, stream, ws);
    hipLaunchKernelGGL(k_ropeqk, dim3(512), dim3(256), 0, stream, ws);
    hipLaunchKernelGGL(k_half_p, dim3(8), dim3(256), 0, stream, proj, ws);
    hipLaunchKernelGGL(k_kmax,   dim3(128, 12), dim3(256), 0, stream, ws);
    hipLaunchKernelGGL(k_kctx,   dim3(32, 12, 2), dim3(256), 0, stream, ws);
    hipLaunchKernelGGL(k_ctxt,   dim3(12, 16), dim3(256), 0, stream, ws);   // reduce partials
    hipLaunchKernelGGL(k_local,  dim3(4, 128), dim3(256), 0, stream, ws);   // before k_qout!
    hipLaunchKernelGGL(k_qout,   dim3(128, 12), dim3(256), 0, stream, ws);
    hipLaunchKernelGGL(k_half_wo, dim3(8, 8), dim3(256), 0, stream, Wo, ws); // ctx region -> WoT
    hipLaunchKernelGGL(k_out,    dim3(128, 4), dim3(256), 0, stream, bo, ws, out);
}

// Round 13
// 305.868 us; speedup vs baseline: 1.3630x; 1.3630x over previous
//
#include <hip/hip_runtime.h>

// ---------------- constants ----------------
#define NTOK 8192
#define NORMC 0.35355339059327373f   // 64^-0.25
#define RATIO 0.0625f                // 256^-0.5
#define KEPS  1e-4f

// ws offsets in 4-byte elements (total 27987008)
#define O_KMAX 0                      // 12 x u32 (encoded max)
#define O_KSUM 64                     // 12*256 f32  (zeroed region ends 3136)
#define O_CTX  3136                   // reused as WoT fp16 [512][512] after k_qout
#define O_COS  199744                 // 8192*32
#define O_SIN  461888                 // 8192*32
#define O_Q    724032                 // fp16 [2][8][8192][64] -> ends 4918336
#define O_K    9112640                // fp16 K; later attG fp16 [16384][384]
#define O_XH   13306944               // fp16 x [16384][512] (dead after k_qkv)
#define O_CPART 13306944              // fp16 ctx partials [12][2][32][128][64] in dead XH
#define O_V    17501248               // fp16 V
#define O_QR   21695552               // fp16 RoPE'd Q heads6-7
#define O_KR   22744128               // fp16 RoPE'd K heads6-7
#define O_ATTL 25889856               // fp16 [2][2][8192][64]
#define O_WH   25889856               // fp16 W^T [3][512][512] (dead after k_qkv)
#define O_PH   26938432               // fp16 proj [256][64]
#define O_CTXT 26946624               // fp16 ctxT [12][64][256] -> 27044928
// end of use: 27044928 < 27987008

typedef _Float16 half8 __attribute__((ext_vector_type(8)));
typedef _Float16 half4h __attribute__((ext_vector_type(4)));
typedef float floatx4 __attribute__((ext_vector_type(4)));

__device__ __forceinline__ unsigned encf(float f) {
    unsigned u = __float_as_uint(f);
    return (u & 0x80000000u) ? ~u : (u | 0x80000000u);
}
__device__ __forceinline__ float decf(unsigned u) {
    return (u & 0x80000000u) ? __uint_as_float(u & 0x7fffffffu) : __uint_as_float(~u);
}
__device__ __forceinline__ float sumsq8(half8 h) {
    float s = 0.f;
#pragma unroll
    for (int i = 0; i < 8; i++) { float v = (float)h[i]; s = fmaf(v, v, s); }
    return s;
}

// ---------------- RoPE tables (double precision angles) ----------------
__global__ void k_rope(float* __restrict__ ws) {
    int idx = blockIdx.x * 256 + threadIdx.x;      // 8192*32
    int t = idx >> 5, i = idx & 31;
    double invf = pow(10000.0, -(double)(2 * i) / 64.0);
    double ang = (double)t * invf;
    ws[O_COS + idx] = (float)cos(ang);
    ws[O_SIN + idx] = (float)sin(ang);
}

// ---------------- x -> fp16 ----------------
__launch_bounds__(256)
__global__ void k_half_x(const float* __restrict__ x, float* __restrict__ ws) {
    const int idx = blockIdx.x * 256 + threadIdx.x;   // *8 elements
    const float* p = x + (size_t)idx * 8;
    float4 a = *(const float4*)p, b = *(const float4*)(p + 4);
    half8 h = {(_Float16)a.x, (_Float16)a.y, (_Float16)a.z, (_Float16)a.w,
               (_Float16)b.x, (_Float16)b.y, (_Float16)b.z, (_Float16)b.w};
    *(half8*)((_Float16*)(ws + O_XH) + (size_t)idx * 8) = h;
}

// ---------------- proj -> fp16 [256][64] ----------------
__launch_bounds__(256)
__global__ void k_half_p(const float* __restrict__ proj, float* __restrict__ ws) {
    const int idx = blockIdx.x * 256 + threadIdx.x;
    const float* p = proj + (size_t)idx * 8;
    float4 a = *(const float4*)p, b = *(const float4*)(p + 4);
    half8 h = {(_Float16)a.x, (_Float16)a.y, (_Float16)a.z, (_Float16)a.w,
               (_Float16)b.x, (_Float16)b.y, (_Float16)b.z, (_Float16)b.w};
    *(half8*)((_Float16*)(ws + O_PH) + (size_t)idx * 8) = h;
}

// ---------------- RoPE'd Q/K fp16 for local heads 6..7, precomputed once ----------------
__launch_bounds__(256)
__global__ void k_ropeqk(float* __restrict__ ws) {
    const int idx = blockIdx.x * 256 + threadIdx.x;   // 32768 rows * 4 thr/row
    const int rg = idx >> 2, dqo = (idx & 3) * 16;
    const int b = rg >> 14, lh = (rg >> 13) & 1, n = rg & 8191;
    const int h = 6 + lh;
    const int e = dqo & 31;
    const int comp = (dqo < 32) ? dqo + 32 : dqo - 32;
    const float sgn = (dqo < 32) ? -1.f : 1.f;
    const _Float16* Qs = (const _Float16*)(ws + O_Q) + ((size_t)(b * 8 + h) * 8192 + n) * 64;
    const _Float16* Ks = (const _Float16*)(ws + O_K) + ((size_t)(b * 8 + h) * 8192 + n) * 64;
    _Float16* Qd = (_Float16*)(ws + O_QR) + ((size_t)(b * 2 + lh) * 8192 + n) * 64;
    _Float16* Kd = (_Float16*)(ws + O_KR) + ((size_t)(b * 2 + lh) * 8192 + n) * 64;
    const float* cp = ws + O_COS + n * 32 + e;
    const float* sp = ws + O_SIN + n * 32 + e;
    _Float16 tq[16], tk[16];
#pragma unroll
    for (int w4 = 0; w4 < 4; w4++) {
        float4 c4 = *(const float4*)(cp + 4 * w4);
        float4 s4v = *(const float4*)(sp + 4 * w4);
        half4h qa = *(const half4h*)(Qs + dqo + 4 * w4);
        half4h qb = *(const half4h*)(Qs + comp + 4 * w4);
        half4h ka = *(const half4h*)(Ks + dqo + 4 * w4);
        half4h kb = *(const half4h*)(Ks + comp + 4 * w4);
        tq[4*w4+0] = (_Float16)fmaf(sgn * (float)qb[0], s4v.x, (float)qa[0] * c4.x);
        tq[4*w4+1] = (_Float16)fmaf(sgn * (float)qb[1], s4v.y, (float)qa[1] * c4.y);
        tq[4*w4+2] = (_Float16)fmaf(sgn * (float)qb[2], s4v.z, (float)qa[2] * c4.z);
        tq[4*w4+3] = (_Float16)fmaf(sgn * (float)qb[3], s4v.w, (float)qa[3] * c4.w);
        tk[4*w4+0] = (_Float16)fmaf(sgn * (float)kb[0], s4v.x, (float)ka[0] * c4.x);
        tk[4*w4+1] = (_Float16)fmaf(sgn * (float)kb[1], s4v.y, (float)ka[1] * c4.y);
        tk[4*w4+2] = (_Float16)fmaf(sgn * (float)kb[2], s4v.z, (float)ka[2] * c4.z);
        tk[4*w4+3] = (_Float16)fmaf(sgn * (float)kb[3], s4v.w, (float)ka[3] * c4.w);
    }
    *(half8*)(Qd + dqo)     = *(half8*)&tq[0];
    *(half8*)(Qd + dqo + 8) = *(half8*)&tq[8];
    *(half8*)(Kd + dqo)     = *(half8*)&tk[0];
    *(half8*)(Kd + dqo + 8) = *(half8*)&tk[8];
}

// ---------------- ctx partials fp16 [12][2][32][128][64] -> ctxT fp16 [12][64][256] ------
__launch_bounds__(256)
__global__ void k_ctxt(float* __restrict__ ws) {
    __shared__ float T[16][65];
    const int bh = blockIdx.x, j0 = blockIdx.y * 16;      // 16 j per block
    const int jh = j0 >> 7, jrel0 = j0 & 127;
    const _Float16* __restrict__ pp =
        (const _Float16*)(ws + O_CPART) + ((size_t)(bh * 2 + jh) * 32) * 8192;
    _Float16* __restrict__ ct = (_Float16*)(ws + O_CTXT) + (size_t)bh * 16384;
    const int tid = threadIdx.x;
    const int lx = tid & 63, ly = tid >> 6;               // lx=d, ly covers 4 j
#pragma unroll
    for (int i = 0; i < 4; i++) {
        const int jl = ly * 4 + i;
        float s = 0.f;
#pragma unroll 8
        for (int sl = 0; sl < 32; sl++)
            s += (float)pp[((size_t)sl * 128 + jrel0 + jl) * 64 + lx];
        T[jl][lx] = s;
    }
    __syncthreads();
    const int d = tid >> 2, j4 = (tid & 3) * 4;
    half4h v;
#pragma unroll
    for (int ii = 0; ii < 4; ii++) v[ii] = (_Float16)T[j4 + ii][d];
    *(half4h*)(ct + d * 256 + j0 + j4) = v;
}

// ---------------- W -> fp16, transposed to [n][k] ----------------
__launch_bounds__(256)
__global__ void k_half_w(const float* __restrict__ Wq,
                         const float* __restrict__ Wk,
                         const float* __restrict__ Wv,
                         float* __restrict__ ws) {
    __shared__ float T[64][65];
    const int z = blockIdx.z;
    const float* __restrict__ W = (z == 0) ? Wq : ((z == 1) ? Wk : Wv);
    _Float16* __restrict__ Wt = (_Float16*)(ws + O_WH) + (size_t)z * 262144;
    const int k0 = blockIdx.x * 64, n0 = blockIdx.y * 64;
    const int lx = threadIdx.x & 63, ly = threadIdx.x >> 6;
#pragma unroll
    for (int i = 0; i < 16; i++) {
        const int kk = ly * 16 + i;
        T[lx][kk] = W[(k0 + kk) * 512 + n0 + lx];
    }
    __syncthreads();
#pragma unroll
    for (int i = 0; i < 16; i++) {
        const int nn = ly * 16 + i;
        Wt[(n0 + nn) * 512 + k0 + lx] = (_Float16)T[nn][lx];
    }
}

// ---------------- Wo -> fp16 transposed [n][k], into dead ctx region ----------------
__launch_bounds__(256)
__global__ void k_half_wo(const float* __restrict__ Wo, float* __restrict__ ws) {
    __shared__ float T[64][65];
    _Float16* __restrict__ Wt = (_Float16*)(ws + O_CTX);
    const int k0 = blockIdx.x * 64, n0 = blockIdx.y * 64;
    const int lx = threadIdx.x & 63, ly = threadIdx.x >> 6;
#pragma unroll
    for (int i = 0; i < 16; i++) {
        const int kk = ly * 16 + i;
        T[lx][kk] = Wo[(k0 + kk) * 512 + n0 + lx];
    }
    __syncthreads();
#pragma unroll
    for (int i = 0; i < 16; i++) {
        const int nn = ly * 16 + i;
        Wt[(n0 + nn) * 512 + k0 + lx] = (_Float16)T[nn][lx];
    }
}

// ---------------- QKV projection via fp16 MFMA (coalesced LDS-restaged epilogue) --------
__launch_bounds__(256)
__global__ void k_qkv(float* __restrict__ ws) {
    __shared__ _Float16 SM[2 * 128 * 72];    // Ah | Bh; reused as out tile [128][136]
    _Float16* Ah = SM;
    _Float16* Bh = SM + 128 * 72;
    const int z = blockIdx.z;
    const _Float16* __restrict__ xh = (const _Float16*)(ws + O_XH);
    const _Float16* __restrict__ Wt = (const _Float16*)(ws + O_WH) + (size_t)z * 262144;
    _Float16* __restrict__ out = (_Float16*)(ws + ((z == 0) ? O_Q : ((z == 1) ? O_K : O_V)));
    const int r0 = blockIdx.x * 128, c0 = blockIdx.y * 128;
    const int tid = threadIdx.x;
    const int wv = tid >> 6, lane = tid & 63, lm = lane & 15, lq = lane >> 4;
    const int srow = tid >> 1, skoff = (tid & 1) * 32;
    floatx4 acc[2][8];
#pragma unroll
    for (int m = 0; m < 2; m++)
#pragma unroll
        for (int n = 0; n < 8; n++) acc[m][n] = (floatx4){0.f, 0.f, 0.f, 0.f};

    for (int c = 0; c < 8; c++) {
        const int k0 = c * 64;
        {
            const _Float16* ap = xh + (size_t)(r0 + srow) * 512 + k0 + skoff;
#pragma unroll
            for (int q = 0; q < 4; q++)
                *(uint4*)&Ah[srow * 72 + skoff + 8 * q] = *(const uint4*)(ap + 8 * q);
        }
        {
            const _Float16* bp = Wt + (size_t)(c0 + srow) * 512 + k0 + skoff;
#pragma unroll
            for (int q = 0; q < 4; q++)
                *(uint4*)&Bh[srow * 72 + skoff + 8 * q] = *(const uint4*)(bp + 8 * q);
        }
        __syncthreads();
#pragma unroll
        for (int ks = 0; ks < 2; ks++) {
            half8 af[2], bf[8];
            af[0] = *(half8*)&Ah[(wv * 32 + lm) * 72 + ks * 32 + lq * 8];
            af[1] = *(half8*)&Ah[(wv * 32 + 16 + lm) * 72 + ks * 32 + lq * 8];
#pragma unroll
            for (int n = 0; n < 8; n++)
                bf[n] = *(half8*)&Bh[(n * 16 + lm) * 72 + ks * 32 + lq * 8];
#pragma unroll
            for (int m = 0; m < 2; m++)
#pragma unroll
                for (int n = 0; n < 8; n++)
                    acc[m][n] = __builtin_amdgcn_mfma_f32_16x16x32_f16(af[m], bf[n], acc[m][n], 0, 0, 0);
        }
        __syncthreads();
    }
    // epilogue: restage C tile into SM [128][136] fp16 then coalesced 16B stores
    // (safe: last loop iteration ended with __syncthreads())
#pragma unroll
    for (int n = 0; n < 8; n++)
#pragma unroll
        for (int m = 0; m < 2; m++)
#pragma unroll
            for (int j = 0; j < 4; j++)
                SM[(wv * 32 + m * 16 + lq * 4 + j) * 136 + n * 16 + lm] =
                    (_Float16)acc[m][n][j];
    __syncthreads();
    const int bi = r0 >> 13;
    const int orow = tid >> 1, oh2 = tid & 1;
    const int ng = (r0 + orow) & 8191;
    const int hh = (c0 >> 6) + oh2;
    _Float16* op = out + ((size_t)(bi * 8 + hh) * 8192 + ng) * 64;
#pragma unroll
    for (int q = 0; q < 8; q++)
        *(uint4*)(op + q * 8) = *(uint4*)&SM[orow * 136 + oh2 * 64 + q * 8];
}

// ---------------- key-side global max of dd = norm*(K.projT) (fp16 MFMA) ----------------
__launch_bounds__(256)
__global__ void k_kmax(float* __restrict__ ws) {
    __shared__ _Float16 Kh[64 * 68];
    __shared__ unsigned bmax;
    const int bh = blockIdx.y, b = bh / 6, h = bh % 6;
    const _Float16* __restrict__ Kp = (const _Float16*)(ws + O_K) + (size_t)(b * 8 + h) * 8192 * 64;
    const _Float16* __restrict__ projh = (const _Float16*)(ws + O_PH);
    const int n0 = blockIdx.x * 64;
    const int tid = threadIdx.x;
    const int wv = tid >> 6, lane = tid & 63, lm = lane & 15, lq = lane >> 4;
    if (tid == 0) bmax = 0u;
    {
        const int r = tid >> 2, dq = (tid & 3) * 16;
        const _Float16* kpp = Kp + (size_t)(n0 + r) * 64 + dq;
        *(uint4*)&Kh[r * 68 + dq]     = *(const uint4*)(kpp);
        *(uint4*)&Kh[r * 68 + dq + 8] = *(const uint4*)(kpp + 8);
    }
    __syncthreads();
    floatx4 s4[4][4];
#pragma unroll
    for (int nt = 0; nt < 4; nt++)
#pragma unroll
        for (int jt = 0; jt < 4; jt++) s4[nt][jt] = (floatx4){0.f, 0.f, 0.f, 0.f};
#pragma unroll
    for (int ks = 0; ks < 2; ks++) {
        half8 af[4], bf[4];
#pragma unroll
        for (int nt = 0; nt < 4; nt++)
            af[nt] = *(half8*)&Kh[(nt * 16 + lm) * 68 + ks * 32 + lq * 8];
#pragma unroll
        for (int jt = 0; jt < 4; jt++)
            bf[jt] = *(const half8*)(projh + (wv * 64 + jt * 16 + lm) * 64 + ks * 32 + lq * 8);
#pragma unroll
        for (int nt = 0; nt < 4; nt++)
#pragma unroll
            for (int jt = 0; jt < 4; jt++)
                s4[nt][jt] = __builtin_amdgcn_mfma_f32_16x16x32_f16(af[nt], bf[jt], s4[nt][jt], 0, 0, 0);
    }
    float m = -1e30f;
#pragma unroll
    for (int nt = 0; nt < 4; nt++)
#pragma unroll
        for (int jt = 0; jt < 4; jt++)
#pragma unroll
            for (int r = 0; r < 4; r++) m = fmaxf(m, s4[nt][jt][r]);
    m = fmaxf(m, __shfl_xor(m, 1, 64));
    m = fmaxf(m, __shfl_xor(m, 2, 64));
    m = fmaxf(m, __shfl_xor(m, 4, 64));
    m = fmaxf(m, __shfl_xor(m, 8, 64));
    m = fmaxf(m, __shfl_xor(m, 16, 64));
    m = fmaxf(m, __shfl_xor(m, 32, 64));
    if (lane == 0) atomicMax(&bmax, encf(m * NORMC));
    __syncthreads();
    if (tid == 0) atomicMax((unsigned*)ws + O_KMAX + bh, bmax);
}

// ---------------- key-side: kp, k_sum, ctx partials (fp16 MFMA, coalesced flush) --------
__launch_bounds__(256)
__global__ void k_kctx(float* __restrict__ ws) {
    __shared__ _Float16 Kh[64 * 68];
    __shared__ _Float16 Vt[64 * 68];
    __shared__ _Float16 kpt[128 * 72];   // qp use stride 68; flush restage stride 72
    __shared__ float diag4[64][4];
    __shared__ float ksum_s[128];
    const int bh = blockIdx.y, b = bh / 6, h = bh % 6;
    const int n0 = blockIdx.x * 256;
    const int jh = blockIdx.z;
    const _Float16* __restrict__ Kp = (const _Float16*)(ws + O_K) + (size_t)(b * 8 + h) * 8192 * 64;
    const _Float16* __restrict__ Vp = (const _Float16*)(ws + O_V) + (size_t)(b * 8 + h) * 8192 * 64;
    const _Float16* __restrict__ projh = (const _Float16*)(ws + O_PH);
    const float kmax = decf(((const unsigned*)ws)[O_KMAX + bh]);
    const int tid = threadIdx.x;
    const int wv = tid >> 6, lane = tid & 63, lm = lane & 15, lq = lane >> 4;
    if (tid < 128) ksum_s[tid] = 0.f;

    floatx4 acc[2][4];
#pragma unroll
    for (int jt = 0; jt < 2; jt++)
#pragma unroll
        for (int dt = 0; dt < 4; dt++) acc[jt][dt] = (floatx4){0.f, 0.f, 0.f, 0.f};

    for (int nc = 0; nc < 4; nc++) {
        const int ns = n0 + nc * 64;
        if (nc) __syncthreads();                  // D: prev chunk's LDS reads done
        {   // stage Kh [n][d] fp16 copy + diag partials
            const int r = tid >> 2, dq = (tid & 3) * 16;
            const _Float16* kpp = Kp + (size_t)(ns + r) * 64 + dq;
            half8 h0 = *(const half8*)(kpp);
            half8 h1 = *(const half8*)(kpp + 8);
            *(half8*)&Kh[r * 68 + dq]     = h0;
            *(half8*)&Kh[r * 68 + dq + 8] = h1;
            diag4[r][tid & 3] = sumsq8(h0) + sumsq8(h1);
        }
        {   // stage Vt transposed [d][n]
            const int d = tid & 63, nb = (tid >> 6) * 16;
            _Float16 t[16];
#pragma unroll
            for (int i = 0; i < 16; i++)
                t[i] = Vp[(size_t)(ns + nb + i) * 64 + d];
            *(half8*)&Vt[d * 68 + nb]     = *(half8*)&t[0];
            *(half8*)&Vt[d * 68 + nb + 8] = *(half8*)&t[8];
        }
        __syncthreads();                          // A: staging visible
        floatx4 s4[4][2];
#pragma unroll
        for (int nt = 0; nt < 4; nt++)
#pragma unroll
            for (int jt = 0; jt < 2; jt++) s4[nt][jt] = (floatx4){0.f, 0.f, 0.f, 0.f};
#pragma unroll
        for (int ks = 0; ks < 2; ks++) {
            half8 af[4], bf[2];
#pragma unroll
            for (int nt = 0; nt < 4; nt++)
                af[nt] = *(half8*)&Kh[(nt * 16 + lm) * 68 + ks * 32 + lq * 8];
#pragma unroll
            for (int jt = 0; jt < 2; jt++)
                bf[jt] = *(const half8*)(projh + (jh * 128 + wv * 32 + jt * 16 + lm) * 64 + ks * 32 + lq * 8);
#pragma unroll
            for (int nt = 0; nt < 4; nt++)
#pragma unroll
                for (int jt = 0; jt < 2; jt++)
                    s4[nt][jt] = __builtin_amdgcn_mfma_f32_16x16x32_f16(af[nt], bf[jt], s4[nt][jt], 0, 0, 0);
        }
        float jsum[2] = {0.f, 0.f};
#pragma unroll
        for (int nt = 0; nt < 4; nt++) {
            float dg[4];
#pragma unroll
            for (int rr = 0; rr < 4; rr++) {
                float4 d4 = *(float4*)diag4[nt * 16 + lq * 4 + rr];
                dg[rr] = (d4.x + d4.y + d4.z + d4.w) * 0.0625f;
            }
#pragma unroll
            for (int jt = 0; jt < 2; jt++) {
                half4h kv;
#pragma unroll
                for (int rr = 0; rr < 4; rr++) {
                    float v = RATIO * (__expf(fminf(NORMC * s4[nt][jt][rr] - dg[rr] - kmax, 0.f)) + KEPS);
                    jsum[jt] += v;
                    kv[rr] = (_Float16)v;
                }
                *(half4h*)&kpt[(wv * 32 + jt * 16 + lm) * 68 + nt * 16 + lq * 4] = kv;
            }
        }
#pragma unroll
        for (int jt = 0; jt < 2; jt++)
            atomicAdd(&ksum_s[wv * 32 + jt * 16 + lm], jsum[jt]);
        asm volatile("s_waitcnt lgkmcnt(0)" ::: "memory");
#pragma unroll
        for (int ks = 0; ks < 2; ks++) {
            half8 af[2], bf[4];
#pragma unroll
            for (int jt = 0; jt < 2; jt++)
                af[jt] = *(half8*)&kpt[(wv * 32 + jt * 16 + lm) * 68 + ks * 32 + lq * 8];
#pragma unroll
            for (int dt = 0; dt < 4; dt++)
                bf[dt] = *(half8*)&Vt[(dt * 16 + lm) * 68 + ks * 32 + lq * 8];
#pragma unroll
            for (int jt = 0; jt < 2; jt++)
#pragma unroll
                for (int dt = 0; dt < 4; dt++)
                    acc[jt][dt] = __builtin_amdgcn_mfma_f32_16x16x32_f16(af[jt], bf[dt], acc[jt][dt], 0, 0, 0);
        }
    }
    // RACE FIX: all waves must finish reading kpt (stride 68) before the stride-72
    // restage overwrites overlapping bytes of neighboring waves' rows.
    __syncthreads();
    // restage acc into kpt [128][72] (wave-private rows), then coalesced 16B stores
#pragma unroll
    for (int jt = 0; jt < 2; jt++)
#pragma unroll
        for (int dt = 0; dt < 4; dt++)
#pragma unroll
            for (int rr = 0; rr < 4; rr++)
                kpt[(wv * 32 + jt * 16 + lq * 4 + rr) * 72 + dt * 16 + lm] =
                    (_Float16)acc[jt][dt][rr];
    __syncthreads();   // restage + ksum complete
    _Float16* __restrict__ cp = (_Float16*)(ws + O_CPART) +
        (((size_t)(bh * 2 + jh) * 32 + blockIdx.x) * 128) * 64;
    const int jl = tid >> 1, hf = (tid & 1) * 32;
#pragma unroll
    for (int q = 0; q < 4; q++)
        *(uint4*)(cp + jl * 64 + hf + q * 8) = *(uint4*)&kpt[jl * 72 + hf + q * 8];
    if (tid < 128) atomicAdd(ws + O_KSUM + bh * 256 + jh * 128 + tid, ksum_s[tid]);
}

// ---------------- query-side: dd, rowmax, qp, attG (j-sliced, coalesced epilogue) -------
__launch_bounds__(256)
__global__ void k_qout(float* __restrict__ ws) {
    __shared__ _Float16 Qh[64 * 68];
    __shared__ _Float16 qp_s[64 * 260];   // qp stride 260; reused as out tile stride 72
    __shared__ float ksum_s[256];
    __shared__ float diag4[64][4];
    __shared__ float diag_s[64];
    __shared__ unsigned rmax_s[64];
    __shared__ float denom_s[64];
    const int bh = blockIdx.y, b = bh / 6, h = bh % 6;
    const int n0 = blockIdx.x * 64;
    const _Float16* __restrict__ Qp = (const _Float16*)(ws + O_Q) + (size_t)(b * 8 + h) * 8192 * 64;
    const _Float16* __restrict__ projh = (const _Float16*)(ws + O_PH);
    const _Float16* __restrict__ ct = (const _Float16*)(ws + O_CTXT) + (size_t)bh * 16384;
    _Float16* __restrict__ attG = (_Float16*)(ws + O_K);
    const int tid = threadIdx.x;
    const int wv = tid >> 6, lane = tid & 63, lm = lane & 15, lq = lane >> 4;
    if (tid < 64) { rmax_s[tid] = 0u; denom_s[tid] = 0.f; }
    ksum_s[tid] = ws[O_KSUM + bh * 256 + tid];

    {
        const int r = tid >> 2, dq = (tid & 3) * 16;
        const _Float16* qpp = Qp + (size_t)(n0 + r) * 64 + dq;
        half8 h0 = *(const half8*)(qpp);
        half8 h1 = *(const half8*)(qpp + 8);
        *(half8*)&Qh[r * 68 + dq]     = h0;
        *(half8*)&Qh[r * 68 + dq + 8] = h1;
        diag4[r][tid & 3] = sumsq8(h0) + sumsq8(h1);
    }
    __syncthreads();
    if (tid < 64) {
        float4 d4 = *(float4*)diag4[tid];
        diag_s[tid] = (d4.x + d4.y + d4.z + d4.w) * 0.0625f;
    }
    floatx4 s4[4][4];
#pragma unroll
    for (int nt = 0; nt < 4; nt++)
#pragma unroll
        for (int jt = 0; jt < 4; jt++) s4[nt][jt] = (floatx4){0.f, 0.f, 0.f, 0.f};
#pragma unroll
    for (int ks = 0; ks < 2; ks++) {
        half8 af[4], bf[4];
#pragma unroll
        for (int nt = 0; nt < 4; nt++)
            af[nt] = *(half8*)&Qh[(nt * 16 + lm) * 68 + ks * 32 + lq * 8];
#pragma unroll
        for (int jt = 0; jt < 4; jt++)
            bf[jt] = *(const half8*)(projh + (wv * 64 + jt * 16 + lm) * 64 + ks * 32 + lq * 8);
#pragma unroll
        for (int nt = 0; nt < 4; nt++)
#pragma unroll
            for (int jt = 0; jt < 4; jt++)
                s4[nt][jt] = __builtin_amdgcn_mfma_f32_16x16x32_f16(af[nt], bf[jt], s4[nt][jt], 0, 0, 0);
    }
#pragma unroll
    for (int nt = 0; nt < 4; nt++) {
#pragma unroll
        for (int rr = 0; rr < 4; rr++) {
            float m0 = fmaxf(fmaxf(s4[nt][0][rr], s4[nt][1][rr]),
                             fmaxf(s4[nt][2][rr], s4[nt][3][rr]));
            m0 = fmaxf(m0, __shfl_xor(m0, 1, 64));
            m0 = fmaxf(m0, __shfl_xor(m0, 2, 64));
            m0 = fmaxf(m0, __shfl_xor(m0, 4, 64));
            m0 = fmaxf(m0, __shfl_xor(m0, 8, 64));
            if (lm == 0) atomicMax(&rmax_s[nt * 16 + lq * 4 + rr], encf(m0 * NORMC));
        }
    }
    __syncthreads();
#pragma unroll
    for (int nt = 0; nt < 4; nt++) {
#pragma unroll
        for (int rr = 0; rr < 4; rr++) {
            const int row = nt * 16 + lq * 4 + rr;
            const float rmx = decf(rmax_s[row]);
            const float dgv = diag_s[row];
#pragma unroll
            for (int jt = 0; jt < 4; jt++) {
                const int j = wv * 64 + jt * 16 + lm;
                float v = RATIO * (__expf(fminf(NORMC * s4[nt][jt][rr] - dgv - rmx, 0.f)) + KEPS);
                qp_s[row * 260 + j] = (_Float16)v;
                s4[nt][jt][rr] = v * ksum_s[j];
            }
            float ds = s4[nt][0][rr] + s4[nt][1][rr] + s4[nt][2][rr] + s4[nt][3][rr];
            ds += __shfl_xor(ds, 1, 64);
            ds += __shfl_xor(ds, 2, 64);
            ds += __shfl_xor(ds, 4, 64);
            ds += __shfl_xor(ds, 8, 64);
            if (lm == 0) atomicAdd(&denom_s[row], ds);
        }
    }
    __syncthreads();
    floatx4 acc2[4];
#pragma unroll
    for (int nt = 0; nt < 4; nt++) acc2[nt] = (floatx4){0.f, 0.f, 0.f, 0.f};
#pragma unroll
    for (int ks = 0; ks < 8; ks++) {
        half8 bfv = *(const half8*)(ct + (wv * 16 + lm) * 256 + ks * 32 + lq * 8);
#pragma unroll
        for (int nt = 0; nt < 4; nt++) {
            half8 af = *(half8*)&qp_s[(nt * 16 + lm) * 260 + ks * 32 + lq * 8];
            acc2[nt] = __builtin_amdgcn_mfma_f32_16x16x32_f16(af, bfv, acc2[nt], 0, 0, 0);
        }
    }
    __syncthreads();   // all qp_s reads done -> reuse as out tile [64][72]
#pragma unroll
    for (int nt = 0; nt < 4; nt++) {
#pragma unroll
        for (int rr = 0; rr < 4; rr++) {
            const int row = nt * 16 + lq * 4 + rr;
            const float inv = 1.0f / fmaxf(denom_s[row], 1e-30f);
            qp_s[row * 72 + wv * 16 + lm] = (_Float16)(acc2[nt][rr] * inv);
        }
    }
    __syncthreads();
    const int orow = tid >> 2, od = (tid & 3) * 16;
    _Float16* op = attG + ((size_t)(b * 8192 + n0 + orow)) * 384 + h * 64 + od;
    *(uint4*)(op)     = *(uint4*)&qp_s[orow * 72 + od];
    *(uint4*)(op + 8) = *(uint4*)&qp_s[orow * 72 + od + 8];
}

// ---------------- local windowed attention, heads 6..7 (coalesced epilogue) -------------
__launch_bounds__(256)
__global__ void k_local(float* __restrict__ ws) {
    __shared__ _Float16 Kh[64 * 68];
    __shared__ _Float16 Vt[64 * 68];
    __shared__ _Float16 pT[64 * 72];     // P stride 68; epilogue restage stride 72
    const int bhp = blockIdx.x, b = bhp >> 1, lh = bhp & 1, h = 6 + lh;
    const int tile = blockIdx.y;
    const int w = tile >> 2;
    const int q0 = tile * 64;
    const _Float16* __restrict__ Qr = (const _Float16*)(ws + O_QR) + (size_t)(b * 2 + lh) * 8192 * 64;
    const _Float16* __restrict__ Kr = (const _Float16*)(ws + O_KR) + (size_t)(b * 2 + lh) * 8192 * 64;
    const _Float16* __restrict__ Vb = (const _Float16*)(ws + O_V) + (size_t)(b * 8 + h) * 8192 * 64;
    const int tid = threadIdx.x;
    const int wv = tid >> 6, lane = tid & 63, lm = lane & 15, lq = lane >> 4;
    const int row = tid >> 2, dqo = (tid & 3) * 16;
    const int vd = lane, vnb = wv * 16;

    const _Float16* qrow = Qr + (size_t)(q0 + wv * 16 + lm) * 64 + lq * 8;
    const half8 aq0 = *(const half8*)(qrow);
    const half8 aq1 = *(const half8*)(qrow + 32);

    const int clo = (w == 0) ? 4 : 0;
    const int chi = min(12, 132 - 4 * w);
    half8 kb0, kb1;
    _Float16 vb[16];
    {
        const int kp0 = (w - 1) * 256 + clo * 64;
        const _Float16* kp = Kr + (size_t)(kp0 + row) * 64 + dqo;
        kb0 = *(const half8*)(kp);
        kb1 = *(const half8*)(kp + 8);
#pragma unroll
        for (int i = 0; i < 16; i++) vb[i] = Vb[(size_t)(kp0 + vnb + i) * 64 + vd];
    }
    floatx4 O[4];
#pragma unroll
    for (int df = 0; df < 4; df++) O[df] = (floatx4){0.f, 0.f, 0.f, 0.f};
    float m_run[4] = {-1e30f, -1e30f, -1e30f, -1e30f};
    float l_run[4] = {0.f, 0.f, 0.f, 0.f};

    for (int c = clo; c < chi; c++) {
        if (c > clo) __syncthreads();
        *(half8*)&Kh[row * 68 + dqo]     = kb0;
        *(half8*)&Kh[row * 68 + dqo + 8] = kb1;
        *(half8*)&Vt[vd * 68 + vnb]     = *(half8*)&vb[0];
        *(half8*)&Vt[vd * 68 + vnb + 8] = *(half8*)&vb[8];
        __syncthreads();
        if (c + 1 < chi) {
            const int kp0 = (w - 1) * 256 + (c + 1) * 64;
            const _Float16* kp = Kr + (size_t)(kp0 + row) * 64 + dqo;
            kb0 = *(const half8*)(kp);
            kb1 = *(const half8*)(kp + 8);
#pragma unroll
            for (int i = 0; i < 16; i++) vb[i] = Vb[(size_t)(kp0 + vnb + i) * 64 + vd];
        }
        floatx4 s4[4];
#pragma unroll
        for (int nf = 0; nf < 4; nf++) s4[nf] = (floatx4){0.f, 0.f, 0.f, 0.f};
#pragma unroll
        for (int ks = 0; ks < 2; ks++) {
            half8 aq = ks ? aq1 : aq0;
            half8 bf[4];
#pragma unroll
            for (int nf = 0; nf < 4; nf++)
                bf[nf] = *(half8*)&Kh[(nf * 16 + lm) * 68 + ks * 32 + lq * 8];
#pragma unroll
            for (int nf = 0; nf < 4; nf++)
                s4[nf] = __builtin_amdgcn_mfma_f32_16x16x32_f16(aq, bf[nf], s4[nf], 0, 0, 0);
        }
        float p[4][4];
#pragma unroll
        for (int rr = 0; rr < 4; rr++) {
            float m0 = fmaxf(fmaxf(s4[0][rr], s4[1][rr]), fmaxf(s4[2][rr], s4[3][rr]));
            m0 = fmaxf(m0, __shfl_xor(m0, 1, 64));
            m0 = fmaxf(m0, __shfl_xor(m0, 2, 64));
            m0 = fmaxf(m0, __shfl_xor(m0, 4, 64));
            m0 = fmaxf(m0, __shfl_xor(m0, 8, 64));
            const float mn = fmaxf(m_run[rr], m0 * 0.125f);
            const float al = __expf(m_run[rr] - mn);
            m_run[rr] = mn;
            float rs = 0.f;
#pragma unroll
            for (int nf = 0; nf < 4; nf++) {
                float pv = __expf(fmaf(s4[nf][rr], 0.125f, -mn));
                p[nf][rr] = pv;
                rs += pv;
            }
            l_run[rr] = l_run[rr] * al + rs;
#pragma unroll
            for (int df = 0; df < 4; df++) O[df][rr] *= al;
        }
#pragma unroll
        for (int nf = 0; nf < 4; nf++)
#pragma unroll
            for (int rr = 0; rr < 4; rr++)
                pT[(wv * 16 + lq * 4 + rr) * 68 + nf * 16 + lm] = (_Float16)p[nf][rr];
        asm volatile("s_waitcnt lgkmcnt(0)" ::: "memory");
#pragma unroll
        for (int ks = 0; ks < 2; ks++) {
            half8 ap = *(half8*)&pT[(wv * 16 + lm) * 68 + ks * 32 + lq * 8];
            half8 bf[4];
#pragma unroll
            for (int df = 0; df < 4; df++)
                bf[df] = *(half8*)&Vt[(df * 16 + lm) * 68 + ks * 32 + lq * 8];
#pragma unroll
            for (int df = 0; df < 4; df++)
                O[df] = __builtin_amdgcn_mfma_f32_16x16x32_f16(ap, bf[df], O[df], 0, 0, 0);
        }
    }
#pragma unroll
    for (int rr = 0; rr < 4; rr++) {
        l_run[rr] += __shfl_xor(l_run[rr], 1, 64);
        l_run[rr] += __shfl_xor(l_run[rr], 2, 64);
        l_run[rr] += __shfl_xor(l_run[rr], 4, 64);
        l_run[rr] += __shfl_xor(l_run[rr], 8, 64);
        l_run[rr] = 1.f / fmaxf(l_run[rr], 1e-30f);
    }
    // RACE FIX: all waves must finish reading pT (stride 68) before the stride-72
    // restage overwrites overlapping bytes of neighboring waves' rows.
    __syncthreads();
    // restage O into pT [64][72] (wave-private rows), then coalesced stores
#pragma unroll
    for (int df = 0; df < 4; df++)
#pragma unroll
        for (int rr = 0; rr < 4; rr++)
            pT[(wv * 16 + lq * 4 + rr) * 72 + df * 16 + lm] =
                (_Float16)(O[df][rr] * l_run[rr]);
    __syncthreads();
    _Float16* __restrict__ attL = (_Float16*)(ws + O_ATTL);
    const int qrw = tid >> 2, dseg = (tid & 3) * 16;
    _Float16* op = attL + ((size_t)(b * 2 + lh) * 8192 + q0 + qrw) * 64 + dseg;
    *(uint4*)(op)     = *(uint4*)&pT[qrw * 72 + dseg];
    *(uint4*)(op + 8) = *(uint4*)&pT[qrw * 72 + dseg + 8];
}

// ---------------- output projection + bias (fp16 MFMA) ----------------
__launch_bounds__(256)
__global__ void k_out(const float* __restrict__ bo,
                      const float* __restrict__ ws,
                      float* __restrict__ out) {
    __shared__ _Float16 Ah[128 * 72];
    __shared__ _Float16 Bh[128 * 72];
    const _Float16* __restrict__ attG = (const _Float16*)(ws + O_K);
    const _Float16* __restrict__ attL = (const _Float16*)(ws + O_ATTL);
    const _Float16* __restrict__ WoT = (const _Float16*)(ws + O_CTX);
    const int r0 = blockIdx.x * 128, c0 = blockIdx.y * 128;
    const int tid = threadIdx.x;
    const int wv = tid >> 6, lane = tid & 63, lm = lane & 15, lq = lane >> 4;
    const int srow = tid >> 1, skoff = (tid & 1) * 32;
    floatx4 acc[2][8];
#pragma unroll
    for (int m = 0; m < 2; m++)
#pragma unroll
        for (int n = 0; n < 8; n++) acc[m][n] = (floatx4){0.f, 0.f, 0.f, 0.f};

    for (int c = 0; c < 8; c++) {
        const int k0 = c * 64;
        {
            const int row = r0 + srow;
            const int kk = k0 + skoff;
            const _Float16* ap;
            if (kk < 384) {
                ap = attG + (size_t)row * 384 + kk;
            } else {
                const int bb = row >> 13, nn = row & 8191;
                const int kr = kk - 384;
                ap = attL + ((size_t)(bb * 2 + (kr >> 6)) * 8192 + nn) * 64 + (kr & 63);
            }
#pragma unroll
            for (int q = 0; q < 4; q++)
                *(uint4*)&Ah[srow * 72 + skoff + 8 * q] = *(const uint4*)(ap + 8 * q);
        }
        {
            const _Float16* bp = WoT + (size_t)(c0 + srow) * 512 + k0 + skoff;
#pragma unroll
            for (int q = 0; q < 4; q++)
                *(uint4*)&Bh[srow * 72 + skoff + 8 * q] = *(const uint4*)(bp + 8 * q);
        }
        __syncthreads();
#pragma unroll
        for (int ks = 0; ks < 2; ks++) {
            half8 af[2], bf[8];
            af[0] = *(half8*)&Ah[(wv * 32 + lm) * 72 + ks * 32 + lq * 8];
            af[1] = *(half8*)&Ah[(wv * 32 + 16 + lm) * 72 + ks * 32 + lq * 8];
#pragma unroll
            for (int n = 0; n < 8; n++)
                bf[n] = *(half8*)&Bh[(n * 16 + lm) * 72 + ks * 32 + lq * 8];
#pragma unroll
            for (int m = 0; m < 2; m++)
#pragma unroll
                for (int n = 0; n < 8; n++)
                    acc[m][n] = __builtin_amdgcn_mfma_f32_16x16x32_f16(af[m], bf[n], acc[m][n], 0, 0, 0);
        }
        __syncthreads();
    }
#pragma unroll
    for (int n = 0; n < 8; n++) {
        const int col = c0 + n * 16 + lm;
        const float bias = bo[col];
#pragma unroll
        for (int m = 0; m < 2; m++) {
            const int rbase = r0 + wv * 32 + m * 16 + lq * 4;
#pragma unroll
            for (int j = 0; j < 4; j++)
                out[(size_t)(rbase + j) * 512 + col] = acc[m][n][j] + bias;
        }
    }
}

extern "C" void kernel_launch(void* const* d_in, const int* in_sizes, int n_in,
                              void* d_out, int out_size, void* d_ws, size_t ws_size,
                              hipStream_t stream) {
    const float* x    = (const float*)d_in[0];
    const float* Wq   = (const float*)d_in[1];
    const float* Wk   = (const float*)d_in[2];
    const float* Wv   = (const float*)d_in[3];
    const float* Wo   = (const float*)d_in[4];
    const float* bo   = (const float*)d_in[5];
    const float* proj = (const float*)d_in[6];
    float* ws = (float*)d_ws;
    float* out = (float*)d_out;

    hipMemsetAsync(d_ws, 0, (size_t)3136 * 4, stream);                   // kmax/ksum only
    hipLaunchKernelGGL(k_rope,   dim3(1024), dim3(256), 0, stream, ws);
    hipLaunchKernelGGL(k_half_x, dim3(4096), dim3(256), 0, stream, x, ws);
    hipLaunchKernelGGL(k_half_w, dim3(8, 8, 3), dim3(256), 0, stream, Wq, Wk, Wv, ws);
    hipLaunchKernelGGL(k_qkv,    dim3(128, 4, 3), dim3(256), 0, stream, ws);
    hipLaunchKernelGGL(k_ropeqk, dim3(512), dim3(256), 0, stream, ws);
    hipLaunchKernelGGL(k_half_p, dim3(8), dim3(256), 0, stream, proj, ws);
    hipLaunchKernelGGL(k_kmax,   dim3(128, 12), dim3(256), 0, stream, ws);
    hipLaunchKernelGGL(k_kctx,   dim3(32, 12, 2), dim3(256), 0, stream, ws);
    hipLaunchKernelGGL(k_ctxt,   dim3(12, 16), dim3(256), 0, stream, ws);   // reduce partials
    hipLaunchKernelGGL(k_local,  dim3(4, 128), dim3(256), 0, stream, ws);   // before k_qout!
    hipLaunchKernelGGL(k_qout,   dim3(128, 12), dim3(256), 0, stream, ws);
    hipLaunchKernelGGL(k_half_wo, dim3(8, 8), dim3(256), 0, stream, Wo, ws); // ctx region -> WoT
    hipLaunchKernelGGL(k_out,    dim3(128, 4), dim3(256), 0, stream, bo, ws, out);
}